// Round 14
// baseline (219.726 us; speedup 1.0000x reference)
//
#include <hip/hip_runtime.h>
#include <math.h>

constexpr int B   = 2;
constexpr int N   = 2048;
constexpr int HID = 768;
constexpr int H   = 12;
constexpr int D   = 64;
constexpr int M   = B * N;
constexpr int QKV_ELEMS = B * H * N * D;   // 3,145,728 elems per tensor

typedef __attribute__((ext_vector_type(8))) short s8v;            // 8 x bf16
typedef __attribute__((ext_vector_type(8))) unsigned short u8v;   // 8 x u16
typedef __attribute__((ext_vector_type(4))) float f4v;            // 4 x f32
typedef unsigned short ushort_t;

__device__ __forceinline__ float bf2f(short u) {
    union { unsigned int i; float f; } v;
    v.i = ((unsigned int)(unsigned short)u) << 16;
    return v.f;
}
__device__ __forceinline__ unsigned short f2bf(float f) {
    union { float f; unsigned int i; } v; v.f = f;
    unsigned int r = v.i + 0x7fff + ((v.i >> 16) & 1);   // RNE
    return (unsigned short)(r >> 16);
}
// hot-loop pack: round-half-up — differs from RNE only on exact ties (~2^-16)
__device__ __forceinline__ unsigned short f2bf_fast(float f) {
    union { float f; unsigned int i; } v; v.f = f;
    return (unsigned short)((v.i + 0x8000u) >> 16);
}
// raw 2^x (VOP1 v_exp_f32, register-only asm)
__device__ __forceinline__ float exp2raw(float x) {
    float r;
    asm("v_exp_f32 %0, %1" : "=v"(r) : "v"(x));
    return r;
}
__device__ __forceinline__ f4v mfma16(s8v a, s8v b, f4v c) {
    return __builtin_amdgcn_mfma_f32_16x16x32_bf16(a, b, c, 0, 0, 0);
}
__device__ __forceinline__ void gl2lds16(const void* g, void* l) {
    __builtin_amdgcn_global_load_lds(
        (const __attribute__((address_space(1))) void*)g,
        (__attribute__((address_space(3))) void*)l, 16, 0, 0);
}
__device__ __forceinline__ u8v cvt8(const float* src) {
    float4 a = *(const float4*)src;
    float4 b = *(const float4*)(src + 4);
    u8v o;
    o[0] = f2bf(a.x); o[1] = f2bf(a.y); o[2] = f2bf(a.z); o[3] = f2bf(a.w);
    o[4] = f2bf(b.x); o[5] = f2bf(b.y); o[6] = f2bf(b.z); o[7] = f2bf(b.w);
    return o;
}
__device__ __forceinline__ int clampsrc(int tv) {
    int src = (tv < 0) ? tv + N : tv;
    return (src < 0) ? 0 : ((src > N - 1) ? N - 1 : src);
}
// XOR-swizzled element offset into a [rows][64] bf16 LDS tile.
__device__ __forceinline__ int swz64(int row, int c8) {
    return (row << 6) + ((c8 ^ (row & 7)) << 3);
}

// softmax scale folded into operands: p = 2^(SCL * score) = e^(score/8)
#define SCL 0.18033688011112042f   // 0.125 * log2(e)

// ---------------------------------------------------------------------------
// Convert everything to bf16 / repack.
// ---------------------------------------------------------------------------
constexpr int CVT_C0 = M * HID / 8;
constexpr int CVT_C1 = CVT_C0 + 3 * HID * HID / 8;
constexpr int CVT_C2 = CVT_C1 + H * N * D / 8;
constexpr int CVT_C3 = CVT_C2 + H * N;

__global__ __launch_bounds__(256) void convert_kernel(
    const float* __restrict__ hs,
    const float* __restrict__ Wq, const float* __restrict__ Wk,
    const float* __restrict__ Wv,
    const float* __restrict__ r_emb, const float* __restrict__ r_bias,
    ushort_t* __restrict__ hsb, ushort_t* __restrict__ Wb,
    ushort_t* __restrict__ reb, float* __restrict__ rbt)
{
    const int idx = blockIdx.x * 256 + threadIdx.x;
    if (idx < CVT_C0) {
        *(u8v*)&hsb[(size_t)idx * 8] = cvt8(&hs[(size_t)idx * 8]);
    } else if (idx < CVT_C1) {
        const int j  = idx - CVT_C0;
        const int z  = j / (HID * HID / 8);
        const int jj = j - z * (HID * HID / 8);
        const float* W = (z == 0) ? Wq : ((z == 1) ? Wk : Wv);
        *(u8v*)&Wb[(size_t)z * HID * HID + (size_t)jj * 8] =
            cvt8(&W[(size_t)jj * 8]);
    } else if (idx < CVT_C2) {
        const int k  = idx - CVT_C1;
        const int d0 = (k & 7) * 8;
        const int s  = (k >> 3) & (N - 1);
        const int h  = k >> 14;
        *(u8v*)&reb[(size_t)k * 8] = cvt8(&r_emb[((size_t)s * H + h) * D + d0]);
    } else if (idx < CVT_C3) {
        const int j = idx - CVT_C2;
        const int h = j >> 11;
        const int s = j & (N - 1);
        rbt[j] = r_bias[(size_t)s * H + h];
    }
}

// ---------------------------------------------------------------------------
// QKV projection, bf16 MFMA. v11 (verified): XCD-clustered dispatch remap +
// LDS-transpose epilogue (T aliases staging; coalesced 128B-burst stores).
// Single-buffered staging (dbuf variants NaN'd twice — abandoned).
// ---------------------------------------------------------------------------
__global__ __launch_bounds__(256) void qkv_mfma_kernel(
    const ushort_t* __restrict__ hsb, const ushort_t* __restrict__ Wb,
    const float* __restrict__ bq, const float* __restrict__ bk,
    const float* __restrict__ bv,
    ushort_t* __restrict__ Qo, ushort_t* __restrict__ Ko,
    ushort_t* __restrict__ Vt)
{
    // XCD-clustered remap (576 = 8 XCDs x 72; 72 = 4 m-panels x 18 (n,z))
    const int fid = blockIdx.x + 32 * (blockIdx.y + 6 * blockIdx.z);
    const int xcd = fid & 7;
    const int idx = fid >> 3;            // [0,72)
    const int m0  = (xcd * 4 + (idx & 3)) * 128;
    const int nz  = idx >> 2;            // [0,18)
    const int o0  = (nz % 6) * 128;
    const int z   = nz / 6;

    const ushort_t* Wz = Wb + (size_t)z * HID * HID;
    const float* bias = (z == 0) ? bq : ((z == 1) ? bk : bv);

    // union: staging (Ah 16K | Wh 16K) vs epilogue T[128][136] (34816 B)
    __shared__ __align__(16) char qsm[128 * 136 * 2];
    ushort_t* Ah = (ushort_t*)qsm;              // [128*64]
    ushort_t* Wh = (ushort_t*)(qsm + 16384);    // [128*64]
    ushort_t* T  = (ushort_t*)qsm;              // [128][136] (aliases)
    constexpr int TS = 136;

    const int t    = threadIdx.x;
    const int lane = t & 63;
    const int w    = t >> 6;
    const int quad = lane >> 4;
    const int col  = lane & 15;
    const int x0   = (w >> 1) * 64;
    const int y0   = (w & 1) * 64;

    const ushort_t* Xs = (z == 2) ? Ah : Wh;
    const ushort_t* Ys = (z == 2) ? Wh : Ah;

    f4v acc[16];
    #pragma unroll
    for (int i = 0; i < 16; i++) acc[i] = (f4v){0.f, 0.f, 0.f, 0.f};

    const int srow = w * 32 + (lane >> 3);
    const int scol = lane & 7;

    for (int k0 = 0; k0 < HID; k0 += 64) {
        __syncthreads();
        #pragma unroll
        for (int e = 0; e < 4; e++) {
            const int row = srow + e * 8;
            const int c8  = scol ^ (row & 7);
            gl2lds16(&hsb[(size_t)(m0 + row) * HID + k0 + c8 * 8],
                     (void*)&Ah[(w * 32 + e * 8) * 64]);
            gl2lds16(&Wz[(size_t)(o0 + row) * HID + k0 + c8 * 8],
                     (void*)&Wh[(w * 32 + e * 8) * 64]);
        }
        __syncthreads();

        #pragma unroll
        for (int ks = 0; ks < 2; ks++) {
            s8v xf[4], yf[4];
            #pragma unroll
            for (int tt = 0; tt < 4; tt++) {
                const int xr  = x0 + tt * 16 + col;
                const int xc8 = (ks * 4 + quad) ^ (xr & 7);
                xf[tt] = *(const s8v*)&Xs[xr * 64 + xc8 * 8];
                const int yr  = y0 + tt * 16 + col;
                const int yc8 = (ks * 4 + quad) ^ (yr & 7);
                yf[tt] = *(const s8v*)&Ys[yr * 64 + yc8 * 8];
            }
            #pragma unroll
            for (int xt = 0; xt < 4; xt++)
                #pragma unroll
                for (int yt = 0; yt < 4; yt++)
                    acc[xt * 4 + yt] = mfma16(xf[xt], yf[yt], acc[xt * 4 + yt]);
        }
    }

    // ---- epilogue: acc -> T (bias applied), then coalesced readout ----
    __syncthreads();   // all waves done reading Ah/Wh; safe to alias as T
    if (z < 2) {
        // acc: o' = x0+xt*16+quad*4+reg (4 consecutive), m' = y0+yt*16+col
        #pragma unroll
        for (int xt = 0; xt < 4; xt++) {
            const int ob = o0 + x0 + xt * 16 + quad * 4;
            const float4 bv4 = *(const float4*)&bias[ob];
            #pragma unroll
            for (int yt = 0; yt < 4; yt++) {
                f4v a = acc[xt * 4 + yt];
                ushort4 pq;
                pq.x = f2bf(a[0] + bv4.x);
                pq.y = f2bf(a[1] + bv4.y);
                pq.z = f2bf(a[2] + bv4.z);
                pq.w = f2bf(a[3] + bv4.w);
                const int row = y0 + yt * 16 + col;        // m'
                const int cb  = x0 + xt * 16 + quad * 4;   // o'
                *(ushort4*)&T[row * TS + cb] = pq;
            }
        }
    } else {
        // acc: m' = x0+xt*16+quad*4+reg (4 consecutive), o' = y0+yt*16+col
        #pragma unroll
        for (int yt = 0; yt < 4; yt++) {
            const int o = o0 + y0 + yt * 16 + col;
            const float bs = bias[o];
            #pragma unroll
            for (int xt = 0; xt < 4; xt++) {
                f4v a = acc[xt * 4 + yt];
                ushort4 pq;
                pq.x = f2bf(a[0] + bs);
                pq.y = f2bf(a[1] + bs);
                pq.z = f2bf(a[2] + bs);
                pq.w = f2bf(a[3] + bs);
                const int row = y0 + yt * 16 + col;        // o'
                const int cb  = x0 + xt * 16 + quad * 4;   // m'
                *(ushort4*)&T[row * TS + cb] = pq;
            }
        }
    }
    __syncthreads();

    const int l8 = t & 15;          // 16B chunk within row
    const int rr = t >> 4;          // 16 rows per pass
    const int bb = m0 >> 11;
    if (z < 2) {
        ushort_t* dst = (z == 0) ? Qo : Ko;
        const int ii0 = m0 & (N - 1);
        const int h   = (o0 + l8 * 8) >> 6;
        const int d0  = (l8 * 8) & 63;
        #pragma unroll
        for (int ps = 0; ps < 8; ps++) {
            const int r = ps * 16 + rr;                     // m'
            u8v v = *(u8v*)&T[r * TS + l8 * 8];
            *(u8v*)&dst[(((size_t)bb * H + h) * N + ii0 + r) * D + d0] = v;
        }
    } else {
        const int n0 = m0 & (N - 1);
        #pragma unroll
        for (int ps = 0; ps < 8; ps++) {
            const int r  = ps * 16 + rr;                    // o' (d-dim)
            u8v v = *(u8v*)&T[r * TS + l8 * 8];
            const int dd = o0 + r;
            *(u8v*)&Vt[(((size_t)bb * H + (dd >> 6)) * D + (dd & 63)) * N
                       + n0 + l8 * 8] = v;
        }
    }
}

// ---------------------------------------------------------------------------
// Fused relative attention v9 (verified): LDS-staged K/V, reg prefetch,
// 2-barrier loop, XCD-clustered remap (FETCH 104.7MB -> 12.5MB).
// grid: (N/64, H, B)  block: 256 (4 waves), wave w owns q rows 16w..16w+15.
// ---------------------------------------------------------------------------
__global__ __launch_bounds__(256, 3) void attn_mfma_kernel(
    const ushort_t* __restrict__ Qb, const ushort_t* __restrict__ Kb,
    const ushort_t* __restrict__ Vt, const ushort_t* __restrict__ reb,
    const float* __restrict__ rbt, const float* __restrict__ rwb_g,
    float* __restrict__ out)
{
    // XCD-clustered remap (768 wgs = 8 XCDs x 96; 96 = 3 full (b,h) groups)
    const int fid  = blockIdx.x + 32 * (blockIdx.y + 12 * blockIdx.z);
    const int work = (fid & 7) * 96 + (fid >> 3);
    const int i0   = (work & 31) * 64;
    const int hb   = work >> 5;          // [0,24)
    const int b    = (hb >= 12) ? 1 : 0;
    const int h    = hb - 12 * b;
    const int bh   = b * H + h;

    const ushort_t* Qbh = Qb + (size_t)bh * N * D;
    const ushort_t* Kbh = Kb + (size_t)bh * N * D;
    const ushort_t* Vbh = Vt + (size_t)bh * D * N;   // [d][n]
    const ushort_t* reh = reb + (size_t)h * N * D;   // [s][d]
    const float*    rbh = rbt + (size_t)h * N;

    // LDS: Ks 8192 | Vs 8192 | Res 16384 | SbT 9216 | Rb 512 | QL/Ps 9216
    //      = 51712 B -> 3 blocks/CU
    __shared__ __align__(16) char smem[51712];
    ushort_t* Ks  = (ushort_t*)(smem + 0);               // 64x64 swz [key][d]
    ushort_t* Vs  = (ushort_t*)(smem + 8192);            // 64x64 swz [d][key]
    ushort_t* Res = (ushort_t*)(smem + 16384);           // 128x64 swz ring
    ushort_t (*SbT)[72] = (ushort_t(*)[72])(smem + 32768); // 64x72 (rows-16)
    float*    Rb        = (float*)(smem + 41984);        // 128 ring (prescaled)
    ushort_t (*QL)[72]  = (ushort_t(*)[72])(smem + 42496); // 64x72 (init only)
    ushort_t (*PsAll)[72] = (ushort_t(*)[72])(smem + 42496); // Ps aliases QL

    const int t    = threadIdx.x;
    const int lane = t & 63;
    const int w    = t >> 6;
    const int quad = lane >> 4;
    const int col  = lane & 15;
    ushort_t (*Ps)[72] = PsAll + w * 16;

    // ---- init: Q rows into QL; q64 row into prescaled f32 regs ----
    #pragma unroll
    for (int e = 0; e < 2; e++) {
        const int idx = t + e * 256;
        const int r   = idx >> 3;
        const int d8  = (idx & 7) * 8;
        *(s8v*)&QL[r][d8] = *(const s8v*)&Qbh[(size_t)(i0 + r) * D + d8];
    }
    const int sub = t & 3;             // row-64 dot: 16-d chunk index
    float q64f[16];
    {
        s8v q64a = {0,0,0,0,0,0,0,0}, q64b = {0,0,0,0,0,0,0,0};
        if (i0 + 64 < N) {
            q64a = *(const s8v*)&Qbh[(size_t)(i0 + 64) * D + sub * 16];
            q64b = *(const s8v*)&Qbh[(size_t)(i0 + 64) * D + sub * 16 + 8];
        }
        #pragma unroll
        for (int j = 0; j < 8; j++) {
            q64f[j]     = bf2f(q64a[j]) * SCL;
            q64f[j + 8] = bf2f(q64b[j]) * SCL;
        }
    }
    __syncthreads();

    // qr: Q prescaled by SCL (BD operand); qw: (Q + rwb) prescaled (AC operand)
    s8v qr[2], qw[2];
    #pragma unroll
    for (int ks = 0; ks < 2; ks++) {
        s8v qraw = *(s8v*)&QL[16 * w + col][ks * 32 + quad * 8];
        float4 r0 = *(const float4*)&rwb_g[h * D + ks * 32 + quad * 8];
        float4 r1 = *(const float4*)&rwb_g[h * D + ks * 32 + quad * 8 + 4];
        const float rv[8] = {r0.x, r0.y, r0.z, r0.w, r1.x, r1.y, r1.z, r1.w};
        s8v qq, qs;
        #pragma unroll
        for (int j = 0; j < 8; j++) {
            const float qf = bf2f(qraw[j]);
            qs[j] = (short)f2bf(qf * SCL);
            qq[j] = (short)f2bf((qf + rv[j]) * SCL);
        }
        qr[ks] = qs;
        qw[ks] = qq;
    }

    // ---- prologue: stage tile 0 (K, V, full 128-row Res window, Rb) ----
    {
        #pragma unroll
        for (int e = 0; e < 2; e++) {
            const int idx = t + e * 256;
            const int r   = idx >> 3;
            const int c8  = idx & 7;
            *(s8v*)&Ks[swz64(r, c8)] = *(const s8v*)&Kbh[(size_t)r * D + c8 * 8];
            *(s8v*)&Vs[swz64(r, c8)] = *(const s8v*)&Vbh[(size_t)r * N + c8 * 8];
        }
        #pragma unroll
        for (int e = 0; e < 4; e++) {
            const int idx = t + e * 256;
            const int u   = idx >> 3;
            const int c8  = idx & 7;
            const int src = clampsrc(u - i0 - 65);
            *(s8v*)&Res[swz64(u, c8)] = *(const s8v*)&reh[(size_t)src * D + c8 * 8];
        }
        if (t < 128) Rb[t] = rbh[clampsrc(t - i0 - 65)] * SCL;
    }
    __syncthreads();   // tile 0 staged

    f4v Oacc[4];
    #pragma unroll
    for (int dt = 0; dt < 4; dt++) Oacc[dt] = (f4v){0.f, 0.f, 0.f, 0.f};
    float lacc[4] = {0.f, 0.f, 0.f, 0.f};

    const int u0w  = 48 - 16 * w;
    const int u64  = 16 * w + (lane >> 2);   // row-64 dot: this thread's u
    int off = 0;                              // ring offset = 64*s & 127

    // loop-carried prefetch pointers (tile s+1 bases, advanced each tile)
    const int r0pf = t >> 3;
    const int d8pf = (t & 7) * 8;
    const ushort_t* pK = Kbh + (size_t)(64 + r0pf) * D + d8pf;   // += 64*D
    const ushort_t* pV = Vbh + (size_t)r0pf * N + 64 + d8pf;     // += 64
    int reBase = 64 - i0 - 1;                                    // += 64

    for (int s = 0; s < 32; ++s) {
        const int j0 = s * 64;

        // ======== phase A ========
        // ---- prefetch tile s+1 into regs (latency overlaps compute) ----
        s8v pk[2], pv[2], pr[2];
        float prb = 0.f;
        if (s < 31) {
            #pragma unroll
            for (int e = 0; e < 2; e++) {
                pk[e] = *(const s8v*)(pK + (size_t)e * 32 * D);
                pv[e] = *(const s8v*)(pV + (size_t)e * 32 * N);
                const int src = clampsrc(reBase + r0pf + e * 32);
                pr[e] = *(const s8v*)&reh[(size_t)src * D + d8pf];
            }
            if (t < 64) prb = rbh[clampsrc(reBase + t)] * SCL;
        }

        // ---- AC: Qw @ K^T (prescaled) ----
        __builtin_amdgcn_s_setprio(1);
        f4v acc[4];
        #pragma unroll
        for (int tile = 0; tile < 4; tile++) {
            acc[tile] = (f4v){0.f, 0.f, 0.f, 0.f};
            #pragma unroll
            for (int ks = 0; ks < 2; ks++) {
                s8v kb = *(s8v*)&Ks[swz64(tile * 16 + col, ks * 4 + quad)];
                acc[tile] = mfma16(qw[ks], kb, acc[tile]);
            }
        }
        // ---- BD product -> diagonal SbT (rbv folded into acc init) ----
        #pragma unroll
        for (int tt = 0; tt < 5; tt++) {
            const int u = u0w + tt * 16 + col;
            const float rbv = Rb[(u + off) & 127];
            f4v sb = (f4v){rbv, rbv, rbv, rbv};
            #pragma unroll
            for (int ks = 0; ks < 2; ks++) {
                s8v rb8 = *(s8v*)&Res[swz64((u + off) & 127, ks * 4 + quad)];
                sb = mfma16(qr[ks], rb8, sb);
            }
            #pragma unroll
            for (int reg = 0; reg < 4; reg++) {
                const int rho = 16 * w + quad * 4 + reg;
                const int row = tt * 16 + col + quad * 4 + reg - 16;
                if ((unsigned)row < 64u)         // band edges never read
                    SbT[row][rho] = f2bf_fast(sb[reg]);
            }
        }
        __builtin_amdgcn_s_setprio(0);
        // ---- row 64 (distributed): SbT[u][64] = q64 . res(u) + rb ----
        {
            float part = 0.f;
            const int rp = (u64 + off) & 127;
            s8v r0 = *(s8v*)&Res[swz64(rp, sub * 2)];
            s8v r1 = *(s8v*)&Res[swz64(rp, sub * 2 + 1)];
            #pragma unroll
            for (int j = 0; j < 8; j++) {
                part += q64f[j]     * bf2f(r0[j]);
                part += q64f[j + 8] * bf2f(r1[j]);
            }
            part += __shfl_xor(part, 1, 64);
            part += __shfl_xor(part, 2, 64);
            if (sub == 0)
                SbT[u64][64] = f2bf_fast(part + Rb[rp]);
        }
        __syncthreads();   // alpha: SbT complete; Ks/Res/Rb reads done

        // ======== phase B ========
        // ---- stage Ks/Res/Rb for s+1 (overlaps gather/exp/PV) ----
        if (s < 31) {
            #pragma unroll
            for (int e = 0; e < 2; e++) {
                const int idx = t + e * 256;
                const int r   = idx >> 3;
                const int c8  = idx & 7;
                *(s8v*)&Ks[swz64(r, c8)] = pk[e];
                *(s8v*)&Res[swz64((r + off) & 127, c8)] = pr[e];
            }
            if (t < 64) Rb[(t + off) & 127] = prb;
        }

        // ---- gather (rel_shift) + no-max softmax: p = 2^(acc+bd) ----
        float p[4][4];
        const int rbase = 16 * w + quad * 4;
        #pragma unroll
        for (int tile = 0; tile < 4; tile++) {
            const int cr   = tile * 16 + col;        // SbT row = cp (pre-shifted)
            ushort4 q4a = *(ushort4*)&SbT[cr][rbase];
            ushort_t b4 = SbT[cr][rbase + 4];
            float vf[5];
            vf[0] = bf2f((short)q4a.x); vf[1] = bf2f((short)q4a.y);
            vf[2] = bf2f((short)q4a.z); vf[3] = bf2f((short)q4a.w);
            vf[4] = bf2f((short)b4);
            const int c = (j0 + tile * 16 + col) - (i0 + rbase) - 2;
            #pragma unroll
            for (int reg = 0; reg < 4; reg++) {
                float bd = (reg <= c) ? vf[reg + 1] : vf[reg];
                bd = (c == reg - 1) ? 0.f : bd;
                const float e = exp2raw(acc[tile][reg] + bd);
                p[tile][reg] = e;
                lacc[reg] += e;
            }
        }
        // ---- P -> LDS (wave-private), PV ----
        #pragma unroll
        for (int tile = 0; tile < 4; tile++)
            #pragma unroll
            for (int reg = 0; reg < 4; reg++)
                Ps[quad * 4 + reg][tile * 16 + col] = f2bf_fast(p[tile][reg]);
        __asm__ volatile("s_waitcnt lgkmcnt(0)" ::: "memory");
        __builtin_amdgcn_s_setprio(1);
        #pragma unroll
        for (int dt = 0; dt < 4; dt++) {
            #pragma unroll
            for (int ks = 0; ks < 2; ks++) {
                s8v pf = *(s8v*)&Ps[col][ks * 32 + quad * 8];
                s8v vf = *(s8v*)&Vs[swz64(dt * 16 + col, ks * 4 + quad)];
                Oacc[dt] = mfma16(pf, vf, Oacc[dt]);
            }
        }
        __builtin_amdgcn_s_setprio(0);
        __syncthreads();   // beta: Vs/SbT reads done; stage writes visible

        // ======== phase C ========
        if (s < 31) {
            #pragma unroll
            for (int e = 0; e < 2; e++) {
                const int idx = t + e * 256;
                const int r   = idx >> 3;
                const int c8  = idx & 7;
                *(s8v*)&Vs[swz64(r, c8)] = pv[e];
            }
            off = (off + 64) & 127;
            pK += (size_t)64 * D;
            pV += 64;
            reBase += 64;
        }
        // no barrier: A' never touches Vs; next alpha covers PV' reads
    }

    // ---- final l reduction (16 lanes per row) + epilogue ----
    #pragma unroll
    for (int reg = 0; reg < 4; reg++) {
        #pragma unroll
        for (int msk = 1; msk < 16; msk <<= 1)
            lacc[reg] += __shfl_xor(lacc[reg], msk, 64);
    }
    #pragma unroll
    for (int reg = 0; reg < 4; reg++) {
        const float inv = 1.f / lacc[reg];
        const int row = i0 + 16 * w + quad * 4 + reg;
        const size_t base = ((size_t)b * N + row) * HID + h * D;
        #pragma unroll
        for (int dt = 0; dt < 4; dt++)
            out[base + dt * 16 + col] = Oacc[dt][reg] * inv;
    }
}

// ---------------------------------------------------------------------------
extern "C" void kernel_launch(void* const* d_in, const int* in_sizes, int n_in,
                              void* d_out, int out_size, void* d_ws, size_t ws_size,
                              hipStream_t stream)
{
    (void)in_sizes; (void)n_in; (void)out_size; (void)ws_size;
    const float* hs   = (const float*)d_in[0];
    const float* remb = (const float*)d_in[1];
    const float* rwb  = (const float*)d_in[2];
    const float* rb   = (const float*)d_in[3];
    const float* Wq   = (const float*)d_in[4];
    const float* bq   = (const float*)d_in[5];
    const float* Wk   = (const float*)d_in[6];
    const float* bk   = (const float*)d_in[7];
    const float* Wv   = (const float*)d_in[8];
    const float* bv   = (const float*)d_in[9];
    float* out = (float*)d_out;

    ushort_t* Qb  = (ushort_t*)d_ws;
    ushort_t* Kb  = Qb + QKV_ELEMS;
    ushort_t* Vt  = Kb + QKV_ELEMS;
    ushort_t* reb = Vt + QKV_ELEMS;
    float*    rbt = (float*)(reb + H * N * D);
    ushort_t* hsb = (ushort_t*)(rbt + H * N);
    ushort_t* Wb  = hsb + (size_t)M * HID;

    convert_kernel<<<CVT_C3 / 256, 256, 0, stream>>>(
        hs, Wq, Wk, Wv, remb, rb, hsb, Wb, reb, rbt);
    qkv_mfma_kernel<<<dim3(M / 128, HID / 128, 3), 256, 0, stream>>>(
        hsb, Wb, bq, bk, bv, Qb, Kb, Vt);
    attn_mfma_kernel<<<dim3(N / 64, H, B), 256, 0, stream>>>(
        Qb, Kb, Vt, reb, rbt, rwb, out);
}

// Round 15
// 218.422 us; speedup vs baseline: 1.0060x; 1.0060x over previous
//
#include <hip/hip_runtime.h>
#include <math.h>

constexpr int B   = 2;
constexpr int N   = 2048;
constexpr int HID = 768;
constexpr int H   = 12;
constexpr int D   = 64;
constexpr int M   = B * N;
constexpr int QKV_ELEMS = B * H * N * D;   // 3,145,728 elems per tensor

typedef __attribute__((ext_vector_type(8))) short s8v;            // 8 x bf16
typedef __attribute__((ext_vector_type(8))) unsigned short u8v;   // 8 x u16
typedef __attribute__((ext_vector_type(4))) float f4v;            // 4 x f32
typedef unsigned short ushort_t;

__device__ __forceinline__ float bf2f(short u) {
    union { unsigned int i; float f; } v;
    v.i = ((unsigned int)(unsigned short)u) << 16;
    return v.f;
}
__device__ __forceinline__ unsigned short f2bf(float f) {
    union { float f; unsigned int i; } v; v.f = f;
    unsigned int r = v.i + 0x7fff + ((v.i >> 16) & 1);   // RNE
    return (unsigned short)(r >> 16);
}
// hot-loop pack: round-half-up — differs from RNE only on exact ties (~2^-16)
__device__ __forceinline__ unsigned short f2bf_fast(float f) {
    union { float f; unsigned int i; } v; v.f = f;
    return (unsigned short)((v.i + 0x8000u) >> 16);
}
// raw 2^x (VOP1 v_exp_f32, register-only asm)
__device__ __forceinline__ float exp2raw(float x) {
    float r;
    asm("v_exp_f32 %0, %1" : "=v"(r) : "v"(x));
    return r;
}
__device__ __forceinline__ f4v mfma16(s8v a, s8v b, f4v c) {
    return __builtin_amdgcn_mfma_f32_16x16x32_bf16(a, b, c, 0, 0, 0);
}
__device__ __forceinline__ void gl2lds16(const void* g, void* l) {
    __builtin_amdgcn_global_load_lds(
        (const __attribute__((address_space(1))) void*)g,
        (__attribute__((address_space(3))) void*)l, 16, 0, 0);
}
__device__ __forceinline__ u8v cvt8(const float* src) {
    float4 a = *(const float4*)src;
    float4 b = *(const float4*)(src + 4);
    u8v o;
    o[0] = f2bf(a.x); o[1] = f2bf(a.y); o[2] = f2bf(a.z); o[3] = f2bf(a.w);
    o[4] = f2bf(b.x); o[5] = f2bf(b.y); o[6] = f2bf(b.z); o[7] = f2bf(b.w);
    return o;
}
__device__ __forceinline__ int clampsrc(int tv) {
    int src = (tv < 0) ? tv + N : tv;
    return (src < 0) ? 0 : ((src > N - 1) ? N - 1 : src);
}
// XOR-swizzled element offset into a [rows][64] bf16 LDS tile.
__device__ __forceinline__ int swz64(int row, int c8) {
    return (row << 6) + ((c8 ^ (row & 7)) << 3);
}

// softmax scale folded into operands: p = 2^(SCL * score) = e^(score/8)
#define SCL 0.18033688011112042f   // 0.125 * log2(e)

// ---------------------------------------------------------------------------
// Convert everything to bf16 / repack.
// ---------------------------------------------------------------------------
constexpr int CVT_C0 = M * HID / 8;
constexpr int CVT_C1 = CVT_C0 + 3 * HID * HID / 8;
constexpr int CVT_C2 = CVT_C1 + H * N * D / 8;
constexpr int CVT_C3 = CVT_C2 + H * N;

__global__ __launch_bounds__(256) void convert_kernel(
    const float* __restrict__ hs,
    const float* __restrict__ Wq, const float* __restrict__ Wk,
    const float* __restrict__ Wv,
    const float* __restrict__ r_emb, const float* __restrict__ r_bias,
    ushort_t* __restrict__ hsb, ushort_t* __restrict__ Wb,
    ushort_t* __restrict__ reb, float* __restrict__ rbt)
{
    const int idx = blockIdx.x * 256 + threadIdx.x;
    if (idx < CVT_C0) {
        *(u8v*)&hsb[(size_t)idx * 8] = cvt8(&hs[(size_t)idx * 8]);
    } else if (idx < CVT_C1) {
        const int j  = idx - CVT_C0;
        const int z  = j / (HID * HID / 8);
        const int jj = j - z * (HID * HID / 8);
        const float* W = (z == 0) ? Wq : ((z == 1) ? Wk : Wv);
        *(u8v*)&Wb[(size_t)z * HID * HID + (size_t)jj * 8] =
            cvt8(&W[(size_t)jj * 8]);
    } else if (idx < CVT_C2) {
        const int k  = idx - CVT_C1;
        const int d0 = (k & 7) * 8;
        const int s  = (k >> 3) & (N - 1);
        const int h  = k >> 14;
        *(u8v*)&reb[(size_t)k * 8] = cvt8(&r_emb[((size_t)s * H + h) * D + d0]);
    } else if (idx < CVT_C3) {
        const int j = idx - CVT_C2;
        const int h = j >> 11;
        const int s = j & (N - 1);
        rbt[j] = r_bias[(size_t)s * H + h];
    }
}

// ---------------------------------------------------------------------------
// QKV projection, bf16 MFMA. v11 (verified): XCD-clustered dispatch remap +
// LDS-transpose epilogue (T aliases staging; coalesced 128B-burst stores).
// ---------------------------------------------------------------------------
__global__ __launch_bounds__(256) void qkv_mfma_kernel(
    const ushort_t* __restrict__ hsb, const ushort_t* __restrict__ Wb,
    const float* __restrict__ bq, const float* __restrict__ bk,
    const float* __restrict__ bv,
    ushort_t* __restrict__ Qo, ushort_t* __restrict__ Ko,
    ushort_t* __restrict__ Vt)
{
    // XCD-clustered remap (576 = 8 XCDs x 72; 72 = 4 m-panels x 18 (n,z))
    const int fid = blockIdx.x + 32 * (blockIdx.y + 6 * blockIdx.z);
    const int xcd = fid & 7;
    const int idx = fid >> 3;            // [0,72)
    const int m0  = (xcd * 4 + (idx & 3)) * 128;
    const int nz  = idx >> 2;            // [0,18)
    const int o0  = (nz % 6) * 128;
    const int z   = nz / 6;

    const ushort_t* Wz = Wb + (size_t)z * HID * HID;
    const float* bias = (z == 0) ? bq : ((z == 1) ? bk : bv);

    // union: staging (Ah 16K | Wh 16K) vs epilogue T[128][136] (34816 B)
    __shared__ __align__(16) char qsm[128 * 136 * 2];
    ushort_t* Ah = (ushort_t*)qsm;              // [128*64]
    ushort_t* Wh = (ushort_t*)(qsm + 16384);    // [128*64]
    ushort_t* T  = (ushort_t*)qsm;              // [128][136] (aliases)
    constexpr int TS = 136;

    const int t    = threadIdx.x;
    const int lane = t & 63;
    const int w    = t >> 6;
    const int quad = lane >> 4;
    const int col  = lane & 15;
    const int x0   = (w >> 1) * 64;
    const int y0   = (w & 1) * 64;

    const ushort_t* Xs = (z == 2) ? Ah : Wh;
    const ushort_t* Ys = (z == 2) ? Wh : Ah;

    f4v acc[16];
    #pragma unroll
    for (int i = 0; i < 16; i++) acc[i] = (f4v){0.f, 0.f, 0.f, 0.f};

    const int srow = w * 32 + (lane >> 3);
    const int scol = lane & 7;

    for (int k0 = 0; k0 < HID; k0 += 64) {
        __syncthreads();
        #pragma unroll
        for (int e = 0; e < 4; e++) {
            const int row = srow + e * 8;
            const int c8  = scol ^ (row & 7);
            gl2lds16(&hsb[(size_t)(m0 + row) * HID + k0 + c8 * 8],
                     (void*)&Ah[(w * 32 + e * 8) * 64]);
            gl2lds16(&Wz[(size_t)(o0 + row) * HID + k0 + c8 * 8],
                     (void*)&Wh[(w * 32 + e * 8) * 64]);
        }
        __syncthreads();

        #pragma unroll
        for (int ks = 0; ks < 2; ks++) {
            s8v xf[4], yf[4];
            #pragma unroll
            for (int tt = 0; tt < 4; tt++) {
                const int xr  = x0 + tt * 16 + col;
                const int xc8 = (ks * 4 + quad) ^ (xr & 7);
                xf[tt] = *(const s8v*)&Xs[xr * 64 + xc8 * 8];
                const int yr  = y0 + tt * 16 + col;
                const int yc8 = (ks * 4 + quad) ^ (yr & 7);
                yf[tt] = *(const s8v*)&Ys[yr * 64 + yc8 * 8];
            }
            #pragma unroll
            for (int xt = 0; xt < 4; xt++)
                #pragma unroll
                for (int yt = 0; yt < 4; yt++)
                    acc[xt * 4 + yt] = mfma16(xf[xt], yf[yt], acc[xt * 4 + yt]);
        }
    }

    // ---- epilogue: acc -> T (bias applied), then coalesced readout ----
    __syncthreads();   // all waves done reading Ah/Wh; safe to alias as T
    if (z < 2) {
        // acc: o' = x0+xt*16+quad*4+reg (4 consecutive), m' = y0+yt*16+col
        #pragma unroll
        for (int xt = 0; xt < 4; xt++) {
            const int ob = o0 + x0 + xt * 16 + quad * 4;
            const float4 bv4 = *(const float4*)&bias[ob];
            #pragma unroll
            for (int yt = 0; yt < 4; yt++) {
                f4v a = acc[xt * 4 + yt];
                ushort4 pq;
                pq.x = f2bf(a[0] + bv4.x);
                pq.y = f2bf(a[1] + bv4.y);
                pq.z = f2bf(a[2] + bv4.z);
                pq.w = f2bf(a[3] + bv4.w);
                const int row = y0 + yt * 16 + col;        // m'
                const int cb  = x0 + xt * 16 + quad * 4;   // o'
                *(ushort4*)&T[row * TS + cb] = pq;
            }
        }
    } else {
        // acc: m' = x0+xt*16+quad*4+reg (4 consecutive), o' = y0+yt*16+col
        #pragma unroll
        for (int yt = 0; yt < 4; yt++) {
            const int o = o0 + y0 + yt * 16 + col;
            const float bs = bias[o];
            #pragma unroll
            for (int xt = 0; xt < 4; xt++) {
                f4v a = acc[xt * 4 + yt];
                ushort4 pq;
                pq.x = f2bf(a[0] + bs);
                pq.y = f2bf(a[1] + bs);
                pq.z = f2bf(a[2] + bs);
                pq.w = f2bf(a[3] + bs);
                const int row = y0 + yt * 16 + col;        // o'
                const int cb  = x0 + xt * 16 + quad * 4;   // m'
                *(ushort4*)&T[row * TS + cb] = pq;
            }
        }
    }
    __syncthreads();

    const int l8 = t & 15;          // 16B chunk within row
    const int rr = t >> 4;          // 16 rows per pass
    const int bb = m0 >> 11;
    if (z < 2) {
        ushort_t* dst = (z == 0) ? Qo : Ko;
        const int ii0 = m0 & (N - 1);
        const int h   = (o0 + l8 * 8) >> 6;
        const int d0  = (l8 * 8) & 63;
        #pragma unroll
        for (int ps = 0; ps < 8; ps++) {
            const int r = ps * 16 + rr;                     // m'
            u8v v = *(u8v*)&T[r * TS + l8 * 8];
            *(u8v*)&dst[(((size_t)bb * H + h) * N + ii0 + r) * D + d0] = v;
        }
    } else {
        const int n0 = m0 & (N - 1);
        #pragma unroll
        for (int ps = 0; ps < 8; ps++) {
            const int r  = ps * 16 + rr;                    // o' (d-dim)
            u8v v = *(u8v*)&T[r * TS + l8 * 8];
            const int dd = o0 + r;
            *(u8v*)&Vt[(((size_t)bb * H + (dd >> 6)) * D + (dd & 63)) * N
                       + n0 + l8 * 8] = v;
        }
    }
}

// ---------------------------------------------------------------------------
// Fused relative attention v10: Ps transposed to [kv][q] (per-wave [64][18],
// same 9216B region aliasing QL). P round-trip was 16 scalar b16 writes +
// 8 b128 reads (~176 LDS-cyc/tile/wave); now 8 aligned b32 writes (reg-pairs
// consecutive in q) + 16 conflict-free u16 reads (~139). LDS-pipe model:
// ~780 LDS-cyc/wave/tile x 12 waves x 32 tiles ~ 100% pipe occupancy at the
// measured 116us — this tests that model. All else identical to v9.
// grid: (N/64, H, B)  block: 256 (4 waves), wave w owns q rows 16w..16w+15.
// ---------------------------------------------------------------------------
__global__ __launch_bounds__(256, 3) void attn_mfma_kernel(
    const ushort_t* __restrict__ Qb, const ushort_t* __restrict__ Kb,
    const ushort_t* __restrict__ Vt, const ushort_t* __restrict__ reb,
    const float* __restrict__ rbt, const float* __restrict__ rwb_g,
    float* __restrict__ out)
{
    // XCD-clustered remap (768 wgs = 8 XCDs x 96; 96 = 3 full (b,h) groups)
    const int fid  = blockIdx.x + 32 * (blockIdx.y + 12 * blockIdx.z);
    const int work = (fid & 7) * 96 + (fid >> 3);
    const int i0   = (work & 31) * 64;
    const int hb   = work >> 5;          // [0,24)
    const int b    = (hb >= 12) ? 1 : 0;
    const int h    = hb - 12 * b;
    const int bh   = b * H + h;

    const ushort_t* Qbh = Qb + (size_t)bh * N * D;
    const ushort_t* Kbh = Kb + (size_t)bh * N * D;
    const ushort_t* Vbh = Vt + (size_t)bh * D * N;   // [d][n]
    const ushort_t* reh = reb + (size_t)h * N * D;   // [s][d]
    const float*    rbh = rbt + (size_t)h * N;

    // LDS: Ks 8192 | Vs 8192 | Res 16384 | SbT 9216 | Rb 512 | QL/Ps 9216
    //      = 51712 B -> 3 blocks/CU
    __shared__ __align__(16) char smem[51712];
    ushort_t* Ks  = (ushort_t*)(smem + 0);               // 64x64 swz [key][d]
    ushort_t* Vs  = (ushort_t*)(smem + 8192);            // 64x64 swz [d][key]
    ushort_t* Res = (ushort_t*)(smem + 16384);           // 128x64 swz ring
    ushort_t (*SbT)[72] = (ushort_t(*)[72])(smem + 32768); // 64x72 (rows-16)
    float*    Rb        = (float*)(smem + 41984);        // 128 ring (prescaled)
    ushort_t (*QL)[72]  = (ushort_t(*)[72])(smem + 42496); // 64x72 (init only)
    // Ps (aliases QL region): per-wave [64 kv][18 q-pad], 4x2304B = 9216B
    ushort_t (*PsBase)[18] = (ushort_t(*)[18])(smem + 42496);

    const int t    = threadIdx.x;
    const int lane = t & 63;
    const int w    = t >> 6;
    const int quad = lane >> 4;
    const int col  = lane & 15;
    ushort_t (*Ps)[18] = PsBase + w * 64;

    // ---- init: Q rows into QL; q64 row into prescaled f32 regs ----
    #pragma unroll
    for (int e = 0; e < 2; e++) {
        const int idx = t + e * 256;
        const int r   = idx >> 3;
        const int d8  = (idx & 7) * 8;
        *(s8v*)&QL[r][d8] = *(const s8v*)&Qbh[(size_t)(i0 + r) * D + d8];
    }
    const int sub = t & 3;             // row-64 dot: 16-d chunk index
    float q64f[16];
    {
        s8v q64a = {0,0,0,0,0,0,0,0}, q64b = {0,0,0,0,0,0,0,0};
        if (i0 + 64 < N) {
            q64a = *(const s8v*)&Qbh[(size_t)(i0 + 64) * D + sub * 16];
            q64b = *(const s8v*)&Qbh[(size_t)(i0 + 64) * D + sub * 16 + 8];
        }
        #pragma unroll
        for (int j = 0; j < 8; j++) {
            q64f[j]     = bf2f(q64a[j]) * SCL;
            q64f[j + 8] = bf2f(q64b[j]) * SCL;
        }
    }
    __syncthreads();

    // qr: Q prescaled by SCL (BD operand); qw: (Q + rwb) prescaled (AC operand)
    s8v qr[2], qw[2];
    #pragma unroll
    for (int ks = 0; ks < 2; ks++) {
        s8v qraw = *(s8v*)&QL[16 * w + col][ks * 32 + quad * 8];
        float4 r0 = *(const float4*)&rwb_g[h * D + ks * 32 + quad * 8];
        float4 r1 = *(const float4*)&rwb_g[h * D + ks * 32 + quad * 8 + 4];
        const float rv[8] = {r0.x, r0.y, r0.z, r0.w, r1.x, r1.y, r1.z, r1.w};
        s8v qq, qs;
        #pragma unroll
        for (int j = 0; j < 8; j++) {
            const float qf = bf2f(qraw[j]);
            qs[j] = (short)f2bf(qf * SCL);
            qq[j] = (short)f2bf((qf + rv[j]) * SCL);
        }
        qr[ks] = qs;
        qw[ks] = qq;
    }

    // ---- prologue: stage tile 0 (K, V, full 128-row Res window, Rb) ----
    {
        #pragma unroll
        for (int e = 0; e < 2; e++) {
            const int idx = t + e * 256;
            const int r   = idx >> 3;
            const int c8  = idx & 7;
            *(s8v*)&Ks[swz64(r, c8)] = *(const s8v*)&Kbh[(size_t)r * D + c8 * 8];
            *(s8v*)&Vs[swz64(r, c8)] = *(const s8v*)&Vbh[(size_t)r * N + c8 * 8];
        }
        #pragma unroll
        for (int e = 0; e < 4; e++) {
            const int idx = t + e * 256;
            const int u   = idx >> 3;
            const int c8  = idx & 7;
            const int src = clampsrc(u - i0 - 65);
            *(s8v*)&Res[swz64(u, c8)] = *(const s8v*)&reh[(size_t)src * D + c8 * 8];
        }
        if (t < 128) Rb[t] = rbh[clampsrc(t - i0 - 65)] * SCL;
    }
    __syncthreads();   // tile 0 staged

    f4v Oacc[4];
    #pragma unroll
    for (int dt = 0; dt < 4; dt++) Oacc[dt] = (f4v){0.f, 0.f, 0.f, 0.f};
    float lacc[4] = {0.f, 0.f, 0.f, 0.f};

    const int u0w  = 48 - 16 * w;
    const int u64  = 16 * w + (lane >> 2);   // row-64 dot: this thread's u
    int off = 0;                              // ring offset = 64*s & 127

    // loop-carried prefetch pointers (tile s+1 bases, advanced each tile)
    const int r0pf = t >> 3;
    const int d8pf = (t & 7) * 8;
    const ushort_t* pK = Kbh + (size_t)(64 + r0pf) * D + d8pf;   // += 64*D
    const ushort_t* pV = Vbh + (size_t)r0pf * N + 64 + d8pf;     // += 64
    int reBase = 64 - i0 - 1;                                    // += 64

    for (int s = 0; s < 32; ++s) {
        const int j0 = s * 64;

        // ======== phase A ========
        // ---- prefetch tile s+1 into regs (latency overlaps compute) ----
        s8v pk[2], pv[2], pr[2];
        float prb = 0.f;
        if (s < 31) {
            #pragma unroll
            for (int e = 0; e < 2; e++) {
                pk[e] = *(const s8v*)(pK + (size_t)e * 32 * D);
                pv[e] = *(const s8v*)(pV + (size_t)e * 32 * N);
                const int src = clampsrc(reBase + r0pf + e * 32);
                pr[e] = *(const s8v*)&reh[(size_t)src * D + d8pf];
            }
            if (t < 64) prb = rbh[clampsrc(reBase + t)] * SCL;
        }

        // ---- AC: Qw @ K^T (prescaled) ----
        __builtin_amdgcn_s_setprio(1);
        f4v acc[4];
        #pragma unroll
        for (int tile = 0; tile < 4; tile++) {
            acc[tile] = (f4v){0.f, 0.f, 0.f, 0.f};
            #pragma unroll
            for (int ks = 0; ks < 2; ks++) {
                s8v kb = *(s8v*)&Ks[swz64(tile * 16 + col, ks * 4 + quad)];
                acc[tile] = mfma16(qw[ks], kb, acc[tile]);
            }
        }
        // ---- BD product -> diagonal SbT (rbv folded into acc init) ----
        #pragma unroll
        for (int tt = 0; tt < 5; tt++) {
            const int u = u0w + tt * 16 + col;
            const float rbv = Rb[(u + off) & 127];
            f4v sb = (f4v){rbv, rbv, rbv, rbv};
            #pragma unroll
            for (int ks = 0; ks < 2; ks++) {
                s8v rb8 = *(s8v*)&Res[swz64((u + off) & 127, ks * 4 + quad)];
                sb = mfma16(qr[ks], rb8, sb);
            }
            #pragma unroll
            for (int reg = 0; reg < 4; reg++) {
                const int rho = 16 * w + quad * 4 + reg;
                const int row = tt * 16 + col + quad * 4 + reg - 16;
                if ((unsigned)row < 64u)         // band edges never read
                    SbT[row][rho] = f2bf_fast(sb[reg]);
            }
        }
        __builtin_amdgcn_s_setprio(0);
        // ---- row 64 (distributed): SbT[u][64] = q64 . res(u) + rb ----
        {
            float part = 0.f;
            const int rp = (u64 + off) & 127;
            s8v r0 = *(s8v*)&Res[swz64(rp, sub * 2)];
            s8v r1 = *(s8v*)&Res[swz64(rp, sub * 2 + 1)];
            #pragma unroll
            for (int j = 0; j < 8; j++) {
                part += q64f[j]     * bf2f(r0[j]);
                part += q64f[j + 8] * bf2f(r1[j]);
            }
            part += __shfl_xor(part, 1, 64);
            part += __shfl_xor(part, 2, 64);
            if (sub == 0)
                SbT[u64][64] = f2bf_fast(part + Rb[rp]);
        }
        __syncthreads();   // alpha: SbT complete; Ks/Res/Rb reads done

        // ======== phase B ========
        // ---- stage Ks/Res/Rb for s+1 (overlaps gather/exp/PV) ----
        if (s < 31) {
            #pragma unroll
            for (int e = 0; e < 2; e++) {
                const int idx = t + e * 256;
                const int r   = idx >> 3;
                const int c8  = idx & 7;
                *(s8v*)&Ks[swz64(r, c8)] = pk[e];
                *(s8v*)&Res[swz64((r + off) & 127, c8)] = pr[e];
            }
            if (t < 64) Rb[(t + off) & 127] = prb;
        }

        // ---- gather (rel_shift) + no-max softmax: p = 2^(acc+bd) ----
        float p[4][4];
        const int rbase = 16 * w + quad * 4;
        #pragma unroll
        for (int tile = 0; tile < 4; tile++) {
            const int cr   = tile * 16 + col;        // SbT row = cp (pre-shifted)
            ushort4 q4a = *(ushort4*)&SbT[cr][rbase];
            ushort_t b4 = SbT[cr][rbase + 4];
            float vf[5];
            vf[0] = bf2f((short)q4a.x); vf[1] = bf2f((short)q4a.y);
            vf[2] = bf2f((short)q4a.z); vf[3] = bf2f((short)q4a.w);
            vf[4] = bf2f((short)b4);
            const int c = (j0 + tile * 16 + col) - (i0 + rbase) - 2;
            #pragma unroll
            for (int reg = 0; reg < 4; reg++) {
                float bd = (reg <= c) ? vf[reg + 1] : vf[reg];
                bd = (c == reg - 1) ? 0.f : bd;
                const float e = exp2raw(acc[tile][reg] + bd);
                p[tile][reg] = e;
                lacc[reg] += e;
            }
        }
        // ---- P -> LDS transposed [kv][q]: 8 aligned b32 writes ----
        #pragma unroll
        for (int tile = 0; tile < 4; tile++) {
            const int row = tile * 16 + col;             // kv
            #pragma unroll
            for (int m = 0; m < 2; m++) {
                const unsigned int pk2 =
                    (unsigned int)f2bf_fast(p[tile][2 * m]) |
                    ((unsigned int)f2bf_fast(p[tile][2 * m + 1]) << 16);
                *(unsigned int*)&Ps[row][quad * 4 + 2 * m] = pk2;
            }
        }
        __asm__ volatile("s_waitcnt lgkmcnt(0)" ::: "memory");
        __builtin_amdgcn_s_setprio(1);
        #pragma unroll
        for (int dt = 0; dt < 4; dt++) {
            #pragma unroll
            for (int ks = 0; ks < 2; ks++) {
                s8v pf;
                #pragma unroll
                for (int j = 0; j < 8; j++)
                    pf[j] = (short)Ps[ks * 32 + quad * 8 + j][col];
                s8v vf = *(s8v*)&Vs[swz64(dt * 16 + col, ks * 4 + quad)];
                Oacc[dt] = mfma16(pf, vf, Oacc[dt]);
            }
        }
        __builtin_amdgcn_s_setprio(0);
        __syncthreads();   // beta: Vs/SbT reads done; stage writes visible

        // ======== phase C ========
        if (s < 31) {
            #pragma unroll
            for (int e = 0; e < 2; e++) {
                const int idx = t + e * 256;
                const int r   = idx >> 3;
                const int c8  = idx & 7;
                *(s8v*)&Vs[swz64(r, c8)] = pv[e];
            }
            off = (off + 64) & 127;
            pK += (size_t)64 * D;
            pV += 64;
            reBase += 64;
        }
        // no barrier: A' never touches Vs; next alpha covers PV' reads
    }

    // ---- final l reduction (16 lanes per row) + epilogue ----
    #pragma unroll
    for (int reg = 0; reg < 4; reg++) {
        #pragma unroll
        for (int msk = 1; msk < 16; msk <<= 1)
            lacc[reg] += __shfl_xor(lacc[reg], msk, 64);
    }
    #pragma unroll
    for (int reg = 0; reg < 4; reg++) {
        const float inv = 1.f / lacc[reg];
        const int row = i0 + 16 * w + quad * 4 + reg;
        const size_t base = ((size_t)b * N + row) * HID + h * D;
        #pragma unroll
        for (int dt = 0; dt < 4; dt++)
            out[base + dt * 16 + col] = Oacc[dt][reg] * inv;
    }
}

// ---------------------------------------------------------------------------
extern "C" void kernel_launch(void* const* d_in, const int* in_sizes, int n_in,
                              void* d_out, int out_size, void* d_ws, size_t ws_size,
                              hipStream_t stream)
{
    (void)in_sizes; (void)n_in; (void)out_size; (void)ws_size;
    const float* hs   = (const float*)d_in[0];
    const float* remb = (const float*)d_in[1];
    const float* rwb  = (const float*)d_in[2];
    const float* rb   = (const float*)d_in[3];
    const float* Wq   = (const float*)d_in[4];
    const float* bq   = (const float*)d_in[5];
    const float* Wk   = (const float*)d_in[6];
    const float* bk   = (const float*)d_in[7];
    const float* Wv   = (const float*)d_in[8];
    const float* bv   = (const float*)d_in[9];
    float* out = (float*)d_out;

    ushort_t* Qb  = (ushort_t*)d_ws;
    ushort_t* Kb  = Qb + QKV_ELEMS;
    ushort_t* Vt  = Kb + QKV_ELEMS;
    ushort_t* reb = Vt + QKV_ELEMS;
    float*    rbt = (float*)(reb + H * N * D);
    ushort_t* hsb = (ushort_t*)(rbt + H * N);
    ushort_t* Wb  = hsb + (size_t)M * HID;

    convert_kernel<<<CVT_C3 / 256, 256, 0, stream>>>(
        hs, Wq, Wk, Wv, remb, rb, hsb, Wb, reb, rbt);
    qkv_mfma_kernel<<<dim3(M / 128, HID / 128, 3), 256, 0, stream>>>(
        hsb, Wb, bq, bk, bv, Qb, Kb, Vt);
    attn_mfma_kernel<<<dim3(N / 64, H, B), 256, 0, stream>>>(
        Qb, Kb, Vt, reb, rbt, rwb, out);
}